// Round 1
// baseline (481.605 us; speedup 1.0000x reference)
//
#include <hip/hip_runtime.h>
#include <hip/hip_bf16.h>
#include <cstdint>

typedef unsigned short u16;
typedef __attribute__((ext_vector_type(8))) __bf16 bf16x8;
typedef __attribute__((ext_vector_type(4))) float f32x4;

#define N_NODES 131072
#define C 64
#define KNB 27
#define BATCH 8
#define EMB 512
#define NGROUP 32
#define GN_EPS 1e-5f

__device__ __forceinline__ void gload_lds16(const void* gsrc, void* ldsdst) {
    __builtin_amdgcn_global_load_lds(
        (const __attribute__((address_space(1))) char*)(unsigned long long)(uintptr_t)gsrc,
        (__attribute__((address_space(3))) char*)(unsigned int)(uintptr_t)ldsdst,
        16, 0, 0);
}

__device__ __forceinline__ float silu_f(float x) {
    return x / (1.0f + __expf(-x));
}

__device__ __forceinline__ u16 f2bf(float x) {
    __hip_bfloat16 h = __float2bfloat16(x);
    return __builtin_bit_cast(u16, h);
}

// ---------------- W fp32 [k][ci][co] -> bf16 transposed [k][co][ci] ----------------
__global__ void prep_w(const float* __restrict__ W1, const float* __restrict__ W2,
                       u16* __restrict__ Wb1, u16* __restrict__ Wb2) {
    int idx = blockIdx.x * 256 + threadIdx.x;
    const int per = KNB * C * C; // 110592
    if (idx >= 2 * per) return;
    const float* src = (idx < per) ? W1 : W2;
    u16* dst = (idx < per) ? Wb1 : Wb2;
    int e = (idx < per) ? idx : idx - per;
    int k = e >> 12;          // /4096
    int rem = e & 4095;
    int co = rem >> 6;
    int ci = rem & 63;
    float v = src[(k * C + ci) * C + co];
    dst[e] = f2bf(v);
}

// ---------------- t = silu(time_emb) @ Wt + bt   [B][64] ----------------
__global__ void time_mlp(const float* __restrict__ te, const float* __restrict__ Wt,
                         const float* __restrict__ bt, float* __restrict__ tv) {
    int t = blockIdx.x * 256 + threadIdx.x; // 0..511
    int b = t >> 6, co = t & 63;
    float acc = bt[co];
    for (int e = 0; e < EMB; ++e) {
        float v = te[b * EMB + e];
        acc += silu_f(v) * Wt[e * C + co];
    }
    tv[t] = acc;
}

// ---------------- GroupNorm stats: sum/sumsq per (b,g), count per b ----------------
__global__ void gn_stats(const float* __restrict__ x, const int* __restrict__ batch_id,
                         float* __restrict__ stats, float* __restrict__ cnt) {
    const int NPB = 256; // nodes per block; grid = N/NPB = 512
    int g = threadIdx.x & 31;
    int r = threadIdx.x >> 5; // 0..7
    int n0 = blockIdx.x * NPB;
    float s = 0.f, ss = 0.f, c = 0.f;
    int cur = -1;
    for (int n = n0 + r; n < n0 + NPB; n += 8) {
        int b = batch_id[n];
        if (b != cur) {
            if (cur >= 0) {
                atomicAdd(&stats[(cur * NGROUP + g) * 2 + 0], s);
                atomicAdd(&stats[(cur * NGROUP + g) * 2 + 1], ss);
                if (g == 0) atomicAdd(&cnt[cur], c);
            }
            cur = b; s = 0.f; ss = 0.f; c = 0.f;
        }
        float2 v = *(const float2*)(x + (size_t)n * C + 2 * g);
        s += v.x + v.y;
        ss += v.x * v.x + v.y * v.y;
        c += 1.f;
    }
    if (cur >= 0) {
        atomicAdd(&stats[(cur * NGROUP + g) * 2 + 0], s);
        atomicAdd(&stats[(cur * NGROUP + g) * 2 + 1], ss);
        if (g == 0) atomicAdd(&cnt[cur], c);
    }
}

// ---------------- normalize + affine + SiLU -> bf16 ----------------
__global__ void gn_apply(const float* __restrict__ x, const int* __restrict__ batch_id,
                         const float* __restrict__ stats, const float* __restrict__ cnt,
                         const float* __restrict__ gamma, const float* __restrict__ beta,
                         u16* __restrict__ out) {
    int idx = blockIdx.x * 256 + threadIdx.x; // N*32 total
    int n = idx >> 5, g = idx & 31;
    int b = batch_id[n];
    float denom = cnt[b] * 2.0f;
    float s = stats[(b * NGROUP + g) * 2 + 0];
    float ss = stats[(b * NGROUP + g) * 2 + 1];
    float mean = s / denom;
    float var = ss / denom - mean * mean;
    float rstd = rsqrtf(var + GN_EPS);
    float2 v = *(const float2*)(x + (size_t)n * C + 2 * g);
    float y0 = (v.x - mean) * rstd * gamma[2 * g + 0] + beta[2 * g + 0];
    float y1 = (v.y - mean) * rstd * gamma[2 * g + 1] + beta[2 * g + 1];
    y0 = silu_f(y0);
    y1 = silu_f(y1);
    ushort2 o;
    o.x = f2bf(y0);
    o.y = f2bf(y1);
    *(ushort2*)(out + (size_t)n * C + 2 * g) = o;
}

// ---------------- gather conv via MFMA bf16 ----------------
// act: [N][64] bf16, Wb: [27][64 co][64 ci] bf16 (transposed slice)
// out[n][co] = sum_k sum_ci act[neigh[n][k]][ci] * W[k][ci][co] (+bias +t[batch] +resid)
template <bool ADD_T, bool ADD_RES>
__global__ __launch_bounds__(256) void conv_kernel(
    const u16* __restrict__ act, const int* __restrict__ neigh,
    const u16* __restrict__ Wb, const float* __restrict__ bias,
    const float* __restrict__ tvec, const int* __restrict__ batch_id,
    const float* __restrict__ resid, float* __restrict__ out) {
    __shared__ u16 Abuf[64 * 64]; // 8 KB: 64 node-rows x 64 ci (chunk-swizzled)
    __shared__ u16 Wbuf[64 * 64]; // 8 KB: 64 co-rows  x 64 ci (chunk-swizzled)

    const int tid = threadIdx.x;
    const int wv = tid >> 6, lane = tid & 63;
    const int n0 = blockIdx.x * 64;

    // staging: absolute 16B-chunk index = wv*128 + i*64 + lane; row = chunk>>3, chunkcol = chunk&7
    const int gc0 = wv * 128 + lane;
    const int gc1 = gc0 + 64;
    const int r0 = gc0 >> 3, c0 = gc0 & 7;
    const int r1 = gc1 >> 3, c1 = gc1 & 7;
    const int sc0 = (c0 ^ (r0 & 7)) << 3; // source element offset (xor swizzle)
    const int sc1 = (c1 ^ (r1 & 7)) << 3;

    const int q = lane >> 4, m = lane & 15;
    const int myrow = wv * 16 + m; // A row for this lane's fragment reads

    f32x4 acc[4] = {};

    const u16* wk = Wb;
    for (int k = 0; k < KNB; ++k) {
        __syncthreads(); // prior MFMA reads done before overwrite
        {
            int nb0 = neigh[(n0 + r0) * KNB + k];
            int nb1 = neigh[(n0 + r1) * KNB + k];
            gload_lds16(act + (size_t)nb0 * C + sc0, Abuf + wv * 1024);
            gload_lds16(act + (size_t)nb1 * C + sc1, Abuf + wv * 1024 + 512);
            gload_lds16(wk + r0 * C + sc0, Wbuf + wv * 1024);
            gload_lds16(wk + r1 * C + sc1, Wbuf + wv * 1024 + 512);
        }
        wk += C * C;
        __syncthreads(); // staging visible (vmcnt drained at barrier)
#pragma unroll
        for (int kk = 0; kk < 2; ++kk) {
            const int lc = kk * 4 + q;
            bf16x8 a = *(const bf16x8*)(Abuf + myrow * C + ((lc ^ (myrow & 7)) << 3));
#pragma unroll
            for (int j = 0; j < 4; ++j) {
                const int co = j * 16 + m;
                bf16x8 b = *(const bf16x8*)(Wbuf + co * C + ((lc ^ (co & 7)) << 3));
                acc[j] = __builtin_amdgcn_mfma_f32_16x16x32_bf16(a, b, acc[j], 0, 0, 0);
            }
        }
    }

    // epilogue: D mapping col=lane&15 (=m), row=(lane>>4)*4+reg
    float bs[4];
#pragma unroll
    for (int j = 0; j < 4; ++j) bs[j] = bias[j * 16 + m];
#pragma unroll
    for (int reg = 0; reg < 4; ++reg) {
        const int n = n0 + wv * 16 + q * 4 + reg;
        int b = 0;
        if (ADD_T) b = batch_id[n];
#pragma unroll
        for (int j = 0; j < 4; ++j) {
            const int co = j * 16 + m;
            float v = acc[j][reg] + bs[j];
            if (ADD_T) v += tvec[b * C + co];
            if (ADD_RES) v += resid[(size_t)n * C + co];
            out[(size_t)n * C + co] = v;
        }
    }
}

extern "C" void kernel_launch(void* const* d_in, const int* in_sizes, int n_in,
                              void* d_out, int out_size, void* d_ws, size_t ws_size,
                              hipStream_t stream) {
    const float* x        = (const float*)d_in[0];
    const float* time_emb = (const float*)d_in[1];
    const int*   batch_id = (const int*)d_in[2];
    const int*   neigh    = (const int*)d_in[3];
    const float* g1       = (const float*)d_in[4];
    const float* be1      = (const float*)d_in[5];
    const float* W1       = (const float*)d_in[6];
    const float* b1       = (const float*)d_in[7];
    const float* Wt       = (const float*)d_in[8];
    const float* bt       = (const float*)d_in[9];
    const float* g2       = (const float*)d_in[10];
    const float* be2      = (const float*)d_in[11];
    const float* W2       = (const float*)d_in[12];
    const float* b2       = (const float*)d_in[13];
    float* out = (float*)d_out;

    char* ws = (char*)d_ws;
    u16*   h1     = (u16*)(ws + 0);                 // 16777216 B
    u16*   h3     = (u16*)(ws + 16777216);          // 16777216 B
    float* h2     = (float*)(ws + 33554432);        // 33554432 B
    u16*   Wb1    = (u16*)(ws + 67108864);          // 221184 B
    u16*   Wb2    = (u16*)(ws + 67330048);          // 221184 B
    float* tvec   = (float*)(ws + 67551232);        // 2048 B
    float* stats1 = (float*)(ws + 67553280);        // 512 floats
    float* cnt1   = stats1 + 512;                   // 8
    float* stats2 = cnt1 + 8;                       // 512
    float* cnt2   = stats2 + 512;                   // 8

    hipMemsetAsync(ws + 67553280, 0, 1040 * sizeof(float), stream);
    prep_w<<<864, 256, 0, stream>>>(W1, W2, Wb1, Wb2);
    time_mlp<<<2, 256, 0, stream>>>(time_emb, Wt, bt, tvec);

    gn_stats<<<512, 256, 0, stream>>>(x, batch_id, stats1, cnt1);
    gn_apply<<<16384, 256, 0, stream>>>(x, batch_id, stats1, cnt1, g1, be1, h1);
    conv_kernel<true, false><<<2048, 256, 0, stream>>>(h1, neigh, Wb1, b1, tvec, batch_id, nullptr, h2);
    gn_stats<<<512, 256, 0, stream>>>(h2, batch_id, stats2, cnt2);
    gn_apply<<<16384, 256, 0, stream>>>(h2, batch_id, stats2, cnt2, g2, be2, h3);
    conv_kernel<false, true><<<2048, 256, 0, stream>>>(h3, neigh, Wb2, b2, nullptr, nullptr, x, out);
}

// Round 2
// 442.814 us; speedup vs baseline: 1.0876x; 1.0876x over previous
//
#include <hip/hip_runtime.h>
#include <hip/hip_bf16.h>
#include <cstdint>

typedef unsigned short u16;
typedef __attribute__((ext_vector_type(8))) __bf16 bf16x8;
typedef __attribute__((ext_vector_type(4))) float f32x4;

#define N_NODES 131072
#define C 64
#define KNB 27
#define BATCH 8
#define EMB 512
#define NGROUP 32
#define GN_EPS 1e-5f

__device__ __forceinline__ void gload_lds16(const void* gsrc, void* ldsdst) {
    __builtin_amdgcn_global_load_lds(
        (const __attribute__((address_space(1))) char*)(unsigned long long)(uintptr_t)gsrc,
        (__attribute__((address_space(3))) char*)(unsigned int)(uintptr_t)ldsdst,
        16, 0, 0);
}

__device__ __forceinline__ float silu_f(float x) {
    return x / (1.0f + __expf(-x));
}

__device__ __forceinline__ u16 f2bf(float x) {
    __hip_bfloat16 h = __float2bfloat16(x);
    return __builtin_bit_cast(u16, h);
}

__device__ __forceinline__ float bf2f(u16 h) {
    unsigned u = ((unsigned)h) << 16;
    return __builtin_bit_cast(float, u);
}

// ============ setup: prep_w + time_mlp + zero stats, one dispatch ============
__global__ void setup_kernel(const float* __restrict__ W1, const float* __restrict__ W2,
                             u16* __restrict__ Wb1, u16* __restrict__ Wb2,
                             const float* __restrict__ te, const float* __restrict__ Wt,
                             const float* __restrict__ bt, float* __restrict__ tvec,
                             float* __restrict__ zeroed) {
    __shared__ float red[256];
    const int bid = blockIdx.x;
    const int t = threadIdx.x;
    if (bid < 216) {
        // W fp32 [k][ci][co] -> bf16 [k][co][ci]; 2*110592 elements, 4 per thread
        const int per = KNB * C * C;
        int e0 = (bid * 256 + t) * 4;
#pragma unroll
        for (int d = 0; d < 4; ++d) {
            int idx = e0 + d;
            const float* src = (idx < per) ? W1 : W2;
            u16* dst = (idx < per) ? Wb1 : Wb2;
            int e = (idx < per) ? idx : idx - per;
            int k = e >> 12;
            int rem = e & 4095;
            int co = rem >> 6;
            int ci = rem & 63;
            dst[e] = f2bf(src[(k * C + ci) * C + co]);
        }
    } else if (bid < 224) {
        // time mlp: one block per batch sample
        int b = bid - 216;
        int co = t & 63, seg = t >> 6;
        float acc = 0.f;
        for (int i = 0; i < 128; ++i) {
            int e = seg * 128 + i;
            float v = te[b * EMB + e];
            acc += silu_f(v) * Wt[e * C + co];
        }
        red[t] = acc;
        __syncthreads();
        if (t < 64) tvec[b * C + t] = red[t] + red[t + 64] + red[t + 128] + red[t + 192] + bt[t];
    } else {
        for (int i = t; i < 1040; i += 256) zeroed[i] = 0.f;
    }
}

// ============ GN stats (fp32 input) ============
__global__ void gn_stats_f32(const float* __restrict__ x, const int* __restrict__ batch_id,
                             float* __restrict__ stats, float* __restrict__ cnt) {
    const int NPB = 256;
    int g = threadIdx.x & 31;
    int r = threadIdx.x >> 5;
    int n0 = blockIdx.x * NPB;
    float s = 0.f, ss = 0.f, c = 0.f;
    int cur = -1;
    for (int n = n0 + r; n < n0 + NPB; n += 8) {
        int b = batch_id[n];
        if (b != cur) {
            if (cur >= 0) {
                atomicAdd(&stats[(cur * NGROUP + g) * 2 + 0], s);
                atomicAdd(&stats[(cur * NGROUP + g) * 2 + 1], ss);
                if (g == 0) atomicAdd(&cnt[cur], c);
            }
            cur = b; s = 0.f; ss = 0.f; c = 0.f;
        }
        float2 v = *(const float2*)(x + (size_t)n * C + 2 * g);
        s += v.x + v.y;
        ss += v.x * v.x + v.y * v.y;
        c += 1.f;
    }
    if (cur >= 0) {
        atomicAdd(&stats[(cur * NGROUP + g) * 2 + 0], s);
        atomicAdd(&stats[(cur * NGROUP + g) * 2 + 1], ss);
        if (g == 0) atomicAdd(&cnt[cur], c);
    }
}

// ============ GN stats (bf16 input) ============
__global__ void gn_stats_bf16(const u16* __restrict__ x, const int* __restrict__ batch_id,
                              float* __restrict__ stats, float* __restrict__ cnt) {
    const int NPB = 256;
    int g = threadIdx.x & 31;
    int r = threadIdx.x >> 5;
    int n0 = blockIdx.x * NPB;
    float s = 0.f, ss = 0.f, c = 0.f;
    int cur = -1;
    for (int n = n0 + r; n < n0 + NPB; n += 8) {
        int b = batch_id[n];
        if (b != cur) {
            if (cur >= 0) {
                atomicAdd(&stats[(cur * NGROUP + g) * 2 + 0], s);
                atomicAdd(&stats[(cur * NGROUP + g) * 2 + 1], ss);
                if (g == 0) atomicAdd(&cnt[cur], c);
            }
            cur = b; s = 0.f; ss = 0.f; c = 0.f;
        }
        ushort2 u = *(const ushort2*)(x + (size_t)n * C + 2 * g);
        float v0 = bf2f(u.x), v1 = bf2f(u.y);
        s += v0 + v1;
        ss += v0 * v0 + v1 * v1;
        c += 1.f;
    }
    if (cur >= 0) {
        atomicAdd(&stats[(cur * NGROUP + g) * 2 + 0], s);
        atomicAdd(&stats[(cur * NGROUP + g) * 2 + 1], ss);
        if (g == 0) atomicAdd(&cnt[cur], c);
    }
}

// ============ normalize + affine + SiLU -> bf16 (fp32 input) ============
__global__ void gn_apply_f32(const float* __restrict__ x, const int* __restrict__ batch_id,
                             const float* __restrict__ stats, const float* __restrict__ cnt,
                             const float* __restrict__ gamma, const float* __restrict__ beta,
                             u16* __restrict__ out) {
    int idx = blockIdx.x * 256 + threadIdx.x;
    int n = idx >> 5, g = idx & 31;
    int b = batch_id[n];
    float denom = cnt[b] * 2.0f;
    float s = stats[(b * NGROUP + g) * 2 + 0];
    float ss = stats[(b * NGROUP + g) * 2 + 1];
    float mean = s / denom;
    float var = ss / denom - mean * mean;
    float rstd = rsqrtf(var + GN_EPS);
    float2 v = *(const float2*)(x + (size_t)n * C + 2 * g);
    float y0 = silu_f((v.x - mean) * rstd * gamma[2 * g + 0] + beta[2 * g + 0]);
    float y1 = silu_f((v.y - mean) * rstd * gamma[2 * g + 1] + beta[2 * g + 1]);
    ushort2 o;
    o.x = f2bf(y0);
    o.y = f2bf(y1);
    *(ushort2*)(out + (size_t)n * C + 2 * g) = o;
}

// ============ normalize + affine + SiLU -> bf16 (bf16 input) ============
__global__ void gn_apply_bf16(const u16* __restrict__ x, const int* __restrict__ batch_id,
                              const float* __restrict__ stats, const float* __restrict__ cnt,
                              const float* __restrict__ gamma, const float* __restrict__ beta,
                              u16* __restrict__ out) {
    int idx = blockIdx.x * 256 + threadIdx.x;
    int n = idx >> 5, g = idx & 31;
    int b = batch_id[n];
    float denom = cnt[b] * 2.0f;
    float s = stats[(b * NGROUP + g) * 2 + 0];
    float ss = stats[(b * NGROUP + g) * 2 + 1];
    float mean = s / denom;
    float var = ss / denom - mean * mean;
    float rstd = rsqrtf(var + GN_EPS);
    ushort2 u = *(const ushort2*)(x + (size_t)n * C + 2 * g);
    float y0 = silu_f((bf2f(u.x) - mean) * rstd * gamma[2 * g + 0] + beta[2 * g + 0]);
    float y1 = silu_f((bf2f(u.y) - mean) * rstd * gamma[2 * g + 1] + beta[2 * g + 1]);
    ushort2 o;
    o.x = f2bf(y0);
    o.y = f2bf(y1);
    *(ushort2*)(out + (size_t)n * C + 2 * g) = o;
}

// ============ gather conv: A gathered to registers, W phase-resident in LDS ============
// act: [N][64] bf16, Wb: [27][co][ci] bf16.
// Block: 512 threads (8 waves), wave = 32 nodes x 64 co, block = 256 nodes. Grid = 512.
// W staged in 4 phases of 7/7/7/6 k-slices (56 KB LDS); k-loop itself is barrier-free.
template <bool ADD_T, bool OUT_F32_RES>
__global__ __launch_bounds__(512, 4) void conv_kernel(
    const u16* __restrict__ act, const int* __restrict__ neigh,
    const u16* __restrict__ Wb, const float* __restrict__ bias,
    const float* __restrict__ tvec, const int* __restrict__ batch_id,
    const float* __restrict__ resid, void* __restrict__ outp) {
    __shared__ u16 Wbuf[7 * 64 * 64]; // 57344 B

    const int tid = threadIdx.x;
    const int w = tid >> 6, lane = tid & 63;
    const int q = lane >> 4, m = lane & 15;
    const int nw = blockIdx.x * 256 + w * 32;

    const int* nrow0 = neigh + (size_t)(nw + m) * KNB;
    const int* nrow1 = neigh + (size_t)(nw + 16 + m) * KNB;

    f32x4 acc[2][4] = {};
    bf16x8 aC[2][2];
    int offn0, offn1;

    // prologue: A for k=0, neigh offsets for k=1
    {
        int o0 = nrow0[0] * C, o1 = nrow1[0] * C;
        aC[0][0] = *(const bf16x8*)(act + o0 + q * 8);
        aC[0][1] = *(const bf16x8*)(act + o0 + 32 + q * 8);
        aC[1][0] = *(const bf16x8*)(act + o1 + q * 8);
        aC[1][1] = *(const bf16x8*)(act + o1 + 32 + q * 8);
        offn0 = nrow0[1] * C;
        offn1 = nrow1[1] * C;
    }

    for (int phase = 0; phase < 4; ++phase) {
        const int k0 = phase * 7;
        const int nk = (phase == 3) ? 6 : 7;
        if (phase) __syncthreads(); // prior phase's Wbuf reads done
        // stage nk slices (nk*512 16B-chunks) via global_load_lds
        const int total = nk * 512;
        for (int it = 0; it < 7; ++it) {
            int cb = it * 512 + w * 64; // wave-uniform chunk base
            if (cb < total) {
                int c = cb + lane;
                int r = c >> 3;       // row = slice*64 + co
                int pos = c & 7;
                int srcc = pos ^ (r & 7);
                gload_lds16(Wb + (((k0 << 6) + r) << 6) + (srcc << 3), Wbuf + cb * 8);
            }
        }
        __syncthreads(); // W visible

        for (int sI = 0; sI < nk; ++sI) {
            const int k = k0 + sI;
            const int kn = k + 1;
            bf16x8 an[2][2];
            if (kn < KNB) {
                an[0][0] = *(const bf16x8*)(act + offn0 + q * 8);
                an[0][1] = *(const bf16x8*)(act + offn0 + 32 + q * 8);
                an[1][0] = *(const bf16x8*)(act + offn1 + q * 8);
                an[1][1] = *(const bf16x8*)(act + offn1 + 32 + q * 8);
            }
            if (kn + 1 < KNB) {
                offn0 = nrow0[kn + 1] * C;
                offn1 = nrow1[kn + 1] * C;
            }
            const u16* wsl = Wbuf + sI * 4096;
#pragma unroll
            for (int kk = 0; kk < 2; ++kk) {
#pragma unroll
                for (int j = 0; j < 4; ++j) {
                    const int co = j * 16 + m;
                    const int lc = kk * 4 + q;
                    bf16x8 b = *(const bf16x8*)(wsl + (co << 6) + ((lc ^ (co & 7)) << 3));
                    acc[0][j] = __builtin_amdgcn_mfma_f32_16x16x32_bf16(aC[0][kk], b, acc[0][j], 0, 0, 0);
                    acc[1][j] = __builtin_amdgcn_mfma_f32_16x16x32_bf16(aC[1][kk], b, acc[1][j], 0, 0, 0);
                }
            }
            if (kn < KNB) {
                aC[0][0] = an[0][0]; aC[0][1] = an[0][1];
                aC[1][0] = an[1][0]; aC[1][1] = an[1][1];
            }
        }
    }

    // epilogue: D mapping col=lane&15 (=m), row=(lane>>4)*4+reg
    float bs[4];
#pragma unroll
    for (int j = 0; j < 4; ++j) bs[j] = bias[j * 16 + m];
#pragma unroll
    for (int s = 0; s < 2; ++s) {
#pragma unroll
        for (int reg = 0; reg < 4; ++reg) {
            const int n = nw + s * 16 + q * 4 + reg;
            int b = 0;
            if (ADD_T) b = batch_id[n];
#pragma unroll
            for (int j = 0; j < 4; ++j) {
                const int co = j * 16 + m;
                float v = acc[s][j][reg] + bs[j];
                if (ADD_T) v += tvec[b * C + co];
                if (OUT_F32_RES) {
                    ((float*)outp)[(size_t)n * C + co] = v + resid[(size_t)n * C + co];
                } else {
                    ((u16*)outp)[(size_t)n * C + co] = f2bf(v);
                }
            }
        }
    }
}

extern "C" void kernel_launch(void* const* d_in, const int* in_sizes, int n_in,
                              void* d_out, int out_size, void* d_ws, size_t ws_size,
                              hipStream_t stream) {
    const float* x        = (const float*)d_in[0];
    const float* time_emb = (const float*)d_in[1];
    const int*   batch_id = (const int*)d_in[2];
    const int*   neigh    = (const int*)d_in[3];
    const float* g1       = (const float*)d_in[4];
    const float* be1      = (const float*)d_in[5];
    const float* W1       = (const float*)d_in[6];
    const float* b1       = (const float*)d_in[7];
    const float* Wt       = (const float*)d_in[8];
    const float* bt       = (const float*)d_in[9];
    const float* g2       = (const float*)d_in[10];
    const float* be2      = (const float*)d_in[11];
    const float* W2       = (const float*)d_in[12];
    const float* b2       = (const float*)d_in[13];
    float* out = (float*)d_out;

    char* ws = (char*)d_ws;
    u16*   h1     = (u16*)(ws + 0);            // 16 MB
    u16*   h2     = (u16*)(ws + 16777216);     // 16 MB
    u16*   h3     = (u16*)(ws + 33554432);     // 16 MB
    u16*   Wb1    = (u16*)(ws + 50331648);     // 221184 B
    u16*   Wb2    = (u16*)(ws + 50552832);     // 221184 B
    float* tvec   = (float*)(ws + 50774016);   // 2048 B
    float* stats1 = (float*)(ws + 50776064);   // 512 f
    float* cnt1   = stats1 + 512;              // 8 f
    float* stats2 = cnt1 + 8;                  // 512 f
    float* cnt2   = stats2 + 512;              // 8 f

    setup_kernel<<<225, 256, 0, stream>>>(W1, W2, Wb1, Wb2, time_emb, Wt, bt, tvec, stats1);
    gn_stats_f32<<<512, 256, 0, stream>>>(x, batch_id, stats1, cnt1);
    gn_apply_f32<<<16384, 256, 0, stream>>>(x, batch_id, stats1, cnt1, g1, be1, h1);
    conv_kernel<true, false><<<512, 512, 0, stream>>>(h1, neigh, Wb1, b1, tvec, batch_id, nullptr, (void*)h2);
    gn_stats_bf16<<<512, 256, 0, stream>>>(h2, batch_id, stats2, cnt2);
    gn_apply_bf16<<<16384, 256, 0, stream>>>(h2, batch_id, stats2, cnt2, g2, be2, h3);
    conv_kernel<false, true><<<512, 512, 0, stream>>>(h3, neigh, Wb2, b2, nullptr, nullptr, x, (void*)d_out);
}